// Round 8
// baseline (224.778 us; speedup 1.0000x reference)
//
#include <hip/hip_runtime.h>
#include <math.h>

// RX gate on qubit 5 of 12, batch 4096 states of dim 4096.
// out_re[i] = c*sr[i] + s*si[i^64];  out_im[i] = c*si[i] - s*sr[i^64]
// (M = c*I - i*s*X_hyd is symmetric; X_hyd is the bit-6 flip permutation.)
//
// v8: completes the {load,store}x{NT,plain} matrix. v5 (NT loads + NT
// stores, kernel ~66us) with stores flipped to plain WRITE-BACK.
// Mechanism under test: outputs (134MB) fit in the 256MiB memory-side L3;
// NT stores push the write stream to HBM inside the kernel's own dispatch
// window (read+write turnaround -> ~4TB/s effective), while write-back
// stores can drain L2->L3 and flush to HBM lazily AFTER the kernel ends.
// Loads stay NT (v5's proven +14us: no read-allocation churn).
//   v3 (plain+plain, ~84us) cannot refute this: its plain stores were
//   paired with churn-dominated plain loads.

#define NQ_N 4096
#define NQ_BATCH 4096

typedef float f32x4 __attribute__((ext_vector_type(4)));

// total f32x4 vecs = 4096*4096/4 = 2^22 ; pairs = 2^21 ; 2 pairs/thread
#define TOTAL_PAIRS (1u << 21)
#define PAIR_OFFSET (1u << 20)   // second pair = first + half the pair space

__global__ __launch_bounds__(256)
void rx_wb_kernel(const f32x4* __restrict__ sr,
                  const f32x4* __restrict__ si,
                  const float* __restrict__ theta_p,
                  f32x4* __restrict__ out_re,
                  f32x4* __restrict__ out_im)
{
    const float half = 0.5f * theta_p[0];
    const float c = cosf(half);
    const float s = sinf(half);

    const unsigned u = blockIdx.x * blockDim.x + threadIdx.x; // pair id (lo half)

    const unsigned p0 = u;
    const unsigned p1 = u + PAIR_OFFSET;

    // pair p -> vec index i with bit4 forced to 0: i = p + (p & ~15)
    const unsigned i0 = p0 + (p0 & ~15u);
    const unsigned j0 = i0 + 16;
    const unsigned i1 = p1 + (p1 & ~15u);
    const unsigned j1 = i1 + 16;

    // 8 independent NONTEMPORAL loads — issued before any use
    const f32x4 rA = __builtin_nontemporal_load(sr + i0);
    const f32x4 rB = __builtin_nontemporal_load(sr + j0);
    const f32x4 mA = __builtin_nontemporal_load(si + i0);
    const f32x4 mB = __builtin_nontemporal_load(si + j0);
    const f32x4 rC = __builtin_nontemporal_load(sr + i1);
    const f32x4 rD = __builtin_nontemporal_load(sr + j1);
    const f32x4 mC = __builtin_nontemporal_load(si + i1);
    const f32x4 mD = __builtin_nontemporal_load(si + j1);

    f32x4 reA, imA, reB, imB, reC, imC, reD, imD;
#pragma unroll
    for (int k = 0; k < 4; ++k) {
        reA[k] = fmaf(c, rA[k],  s * mB[k]);
        imA[k] = fmaf(c, mA[k], -s * rB[k]);
        reB[k] = fmaf(c, rB[k],  s * mA[k]);
        imB[k] = fmaf(c, mB[k], -s * rA[k]);
        reC[k] = fmaf(c, rC[k],  s * mD[k]);
        imC[k] = fmaf(c, mC[k], -s * rD[k]);
        reD[k] = fmaf(c, rD[k],  s * mC[k]);
        imD[k] = fmaf(c, mD[k], -s * rC[k]);
    }

    // plain write-back stores: allocate in L2, drain to memory-side L3,
    // flush to HBM lazily (outputs 134MB < 256MiB L3)
    out_re[i0] = reA;
    out_im[i0] = imA;
    out_re[j0] = reB;
    out_im[j0] = imB;
    out_re[i1] = reC;
    out_im[i1] = imC;
    out_re[j1] = reD;
    out_im[j1] = imD;
}

extern "C" void kernel_launch(void* const* d_in, const int* in_sizes, int n_in,
                              void* d_out, int out_size, void* d_ws, size_t ws_size,
                              hipStream_t stream)
{
    const f32x4* sr = (const f32x4*)d_in[0];
    const f32x4* si = (const f32x4*)d_in[1];
    const float* th = (const float*)d_in[2];

    f32x4* out_re = (f32x4*)d_out;
    f32x4* out_im = out_re + ((size_t)NQ_BATCH * NQ_N / 4);

    const unsigned threads = TOTAL_PAIRS / 2;  // 2 pairs per thread -> 2^20
    const unsigned block = 256;
    const unsigned grid = threads / block;     // 4096

    rx_wb_kernel<<<grid, block, 0, stream>>>(sr, si, th, out_re, out_im);
}